// Round 19
// baseline (523.404 us; speedup 1.0000x reference)
//
#include <hip/hip_runtime.h>
#include <stdint.h>

#define NN 50000
#define NE 800000
#define NG 64
#define CH 128
#define CO 16
#define KH 640    // 5 * 128
#define HRB 4096  // hist node-range per block
#define NRANGE 13 // ceil(NN / HRB)
#define NSLICE 20 // edge slices (13*20 = 260 blocks)
#define SCR 6250  // scatter dst-range per XCD (NN/8)

typedef __attribute__((ext_vector_type(8))) short bf16x8;
typedef __attribute__((ext_vector_type(4))) float f32x4;

__device__ __forceinline__ ushort f2bf(float f) {
  uint32_t u = __float_as_uint(f);
  u += 0x7fffu + ((u >> 16) & 1u);
  return (ushort)(u >> 16);
}
__device__ __forceinline__ float bflo(uint32_t v) { return __uint_as_float(v << 16); }
__device__ __forceinline__ float bfhi(uint32_t v) { return __uint_as_float(v & 0xffff0000u); }

// pack two f32 -> (bf16(hi)<<16)|bf16(lo) in 3 VALU ops (round-half-up)
__device__ __forceinline__ uint32_t pack2bf(float lo, float hi) {
  uint32_t ul = __float_as_uint(lo) + 0x8000u;
  uint32_t uh = __float_as_uint(hi) + 0x8000u;
  return __builtin_amdgcn_perm(uh, ul, 0x07060302u);
}

// ---------------- graph preprocessing ----------------

__global__ __launch_bounds__(1024) void k_hist3(const int4* __restrict__ src4,
                                                const int4* __restrict__ dst4,
                                                uint32_t* __restrict__ part,
                                                int nquad) {
  __shared__ uint32_t h[HRB];
  int range = blockIdx.x / NSLICE;
  int slice = blockIdx.x % NSLICE;
  int lo = range * HRB;
  int q0 = slice * (nquad / NSLICE);
  int q1 = q0 + (nquad / NSLICE);
  for (int i = threadIdx.x; i < HRB; i += 1024) h[i] = 0;
  __syncthreads();
  for (int e = q0 + threadIdx.x; e < q1; e += 1024) {
    int4 s = src4[e];
    int4 d = dst4[e];
    int t;
    t = s.x - lo; if ((unsigned)t < HRB) atomicAdd(&h[t], 1u);
    t = s.y - lo; if ((unsigned)t < HRB) atomicAdd(&h[t], 1u);
    t = s.z - lo; if ((unsigned)t < HRB) atomicAdd(&h[t], 1u);
    t = s.w - lo; if ((unsigned)t < HRB) atomicAdd(&h[t], 1u);
    t = d.x - lo; if ((unsigned)t < HRB) atomicAdd(&h[t], 65536u);
    t = d.y - lo; if ((unsigned)t < HRB) atomicAdd(&h[t], 65536u);
    t = d.z - lo; if ((unsigned)t < HRB) atomicAdd(&h[t], 65536u);
    t = d.w - lo; if ((unsigned)t < HRB) atomicAdd(&h[t], 65536u);
  }
  __syncthreads();
  uint32_t* pr = part + (size_t)slice * NN;
  for (int i = threadIdx.x; i < HRB && lo + i < NN; i += 1024)
    pr[lo + i] = h[i];
}

__global__ __launch_bounds__(256) void k_hreduce(const uint32_t* __restrict__ part,
                                                 uint32_t* __restrict__ packed,
                                                 float* __restrict__ dinv, int n) {
  int i = blockIdx.x * 256 + threadIdx.x;
  if (i >= n) return;
  uint32_t acc = 0;
#pragma unroll
  for (int s = 0; s < NSLICE; ++s) acc += part[(size_t)s * NN + i];
  packed[i] = acc;
  int deg = (int)(acc & 0xffffu);
  dinv[i] = deg > 0 ? rsqrtf((float)deg) : 0.f;
}

__global__ __launch_bounds__(1024) void k_scan_a(const uint32_t* __restrict__ packed,
                                                 int* __restrict__ row_ptr,
                                                 int* __restrict__ bsum, int n) {
  __shared__ int sm[1024];
  int i = blockIdx.x * 1024 + threadIdx.x;
  int v = (i < n) ? (int)(packed[i] >> 16) : 0;
  sm[threadIdx.x] = v;
  __syncthreads();
  for (int off = 1; off < 1024; off <<= 1) {
    int t = (threadIdx.x >= off) ? sm[threadIdx.x - off] : 0;
    __syncthreads();
    sm[threadIdx.x] += t;
    __syncthreads();
  }
  if (i < n) row_ptr[i + 1] = sm[threadIdx.x];
  if (threadIdx.x == 1023) bsum[blockIdx.x] = sm[1023];
}

__global__ void k_scan_b(int* __restrict__ bsum, int nb) {
  if (threadIdx.x == 0) {
    int off = 0;
    for (int i = 0; i < nb; ++i) { int t = bsum[i]; bsum[i] = off; off += t; }
  }
}

__global__ __launch_bounds__(1024) void k_scan_c(const int* __restrict__ bsum,
                                                 int* __restrict__ row_ptr,
                                                 int* __restrict__ fill, int n) {
  int i = blockIdx.x * 1024 + threadIdx.x;
  if (i == 0) { row_ptr[0] = 0; fill[0] = 0; }
  if (i < n) {
    int rp = row_ptr[i + 1] + bsum[blockIdx.x];
    row_ptr[i + 1] = rp;
    if (i + 1 < n) fill[i + 1] = rp;
  }
}

// XCD-partitioned scatter: block (g = blockIdx&7 -> XCD, j = blockIdx>>3).
__global__ __launch_bounds__(1024) void k_scatter2(
    const int* __restrict__ src, const int* __restrict__ dst,
    int* __restrict__ fill, const float* __restrict__ dinv,
    uint32_t* __restrict__ esw, int E) {
  int g = blockIdx.x & 7;
  int j = blockIdx.x >> 3;                 // 0..31
  int lo = g * SCR, hi = min(lo + SCR, NN);
  int per = E / 32;                        // 25000
  int e0 = j * per, e1 = e0 + per;
  for (int e = e0 + threadIdx.x; e < e1; e += 1024) {
    int d = dst[e];
    if (d >= lo && d < hi) {
      int s = src[e];
      int pos = atomicAdd(&fill[d], 1);
      esw[pos] = (uint32_t)s | ((uint32_t)f2bf(dinv[s]) << 16);
    }
  }
}

// ---------------- conversions (fused, identity k-order) ----------------

__global__ __launch_bounds__(256) void k_cvt_all(
    const float* __restrict__ x, const float* __restrict__ W1,
    const float* __restrict__ W2, const float* __restrict__ W3,
    ushort* __restrict__ bufA, ushort* __restrict__ Wt1,
    ushort* __restrict__ Wt2, ushort* __restrict__ Wt3v) {
  const int R1 = NN * 64;
  const int R2 = KH * CH;
  int t = blockIdx.x * 256 + threadIdx.x;
  if (t < R1) {
    int node = t >> 6, p = t & 63;
    float2 v = reinterpret_cast<const float2*>(x)[t];
    *reinterpret_cast<uint32_t*>(bufA + (size_t)node * KH + p * 2) =
        pack2bf(v.x, v.y);
    return;
  }
  t -= R1;
  if (t < 2 * R2) {
    const float* W = (t < R2) ? W1 : W2;
    ushort* Wt = (t < R2) ? Wt1 : Wt2;
    int u = (t < R2) ? t : t - R2;
    int kc = u >> 7, nc = u & 127;
    Wt[(size_t)nc * KH + kc] = f2bf(W[u]);
    return;
  }
  t -= 2 * R2;
  if (t < 5 * CH * CO) {
    int k = t >> 11, r = t & 2047;
    int c = r >> 4, j = r & 15;
    Wt3v[(size_t)(k * CO + j) * CH + c] = f2bf(W3[t]);
  }
}

// ---------------- propagation (bf16, 128 ch), edge-parallel wide gathers ----

__global__ __launch_bounds__(256) void k_prop_bf(
    const ushort* __restrict__ hin, const ushort* __restrict__ tx0,
    ushort* __restrict__ hout, float mscale,
    const int* __restrict__ row_ptr, const uint32_t* __restrict__ esw,
    const float* __restrict__ dinv, int n) {
  int wave = threadIdx.x >> 6;
  int lane = threadIdx.x & 63;
  int node = blockIdx.x * 4 + wave;
  if (node >= n) return;
  int beg = row_ptr[node], end = row_ptr[node + 1];
  int grp = lane >> 4, li = lane & 15;
  const ushort* hc = hin + li * 8;

  float a0 = 0.f, a1 = 0.f, a2 = 0.f, a3 = 0.f;
  float a4 = 0.f, a5 = 0.f, a6 = 0.f, a7 = 0.f;
  float c0 = 0.f, c1 = 0.f, c2 = 0.f, c3 = 0.f;
  float c4 = 0.f, c5 = 0.f, c6 = 0.f, c7 = 0.f;

  for (int e0 = beg; e0 < end; e0 += 16) {
    int ea = e0 + grp;
    uint32_t ua = esw[ea];
    uint32_t ub = esw[ea + 4];
    uint32_t uc = esw[ea + 8];
    uint32_t ud = esw[ea + 12];
    float wa = (ea < end) ? bfhi(ua) : 0.f;
    float wb = (ea + 4 < end) ? bfhi(ub) : 0.f;
    float wc = (ea + 8 < end) ? bfhi(uc) : 0.f;
    float wd = (ea + 12 < end) ? bfhi(ud) : 0.f;
    const uint4 va = *reinterpret_cast<const uint4*>(hc + (size_t)(ua & 0xffffu) * KH);
    const uint4 vb = *reinterpret_cast<const uint4*>(hc + (size_t)(ub & 0xffffu) * KH);
    const uint4 vc = *reinterpret_cast<const uint4*>(hc + (size_t)(uc & 0xffffu) * KH);
    const uint4 vd = *reinterpret_cast<const uint4*>(hc + (size_t)(ud & 0xffffu) * KH);
    a0 = fmaf(wa, bflo(va.x), a0);
    a1 = fmaf(wa, bfhi(va.x), a1);
    a2 = fmaf(wa, bflo(va.y), a2);
    a3 = fmaf(wa, bfhi(va.y), a3);
    a4 = fmaf(wa, bflo(va.z), a4);
    a5 = fmaf(wa, bfhi(va.z), a5);
    a6 = fmaf(wa, bflo(va.w), a6);
    a7 = fmaf(wa, bfhi(va.w), a7);
    a0 = fmaf(wb, bflo(vb.x), a0);
    a1 = fmaf(wb, bfhi(vb.x), a1);
    a2 = fmaf(wb, bflo(vb.y), a2);
    a3 = fmaf(wb, bfhi(vb.y), a3);
    a4 = fmaf(wb, bflo(vb.z), a4);
    a5 = fmaf(wb, bfhi(vb.z), a5);
    a6 = fmaf(wb, bflo(vb.w), a6);
    a7 = fmaf(wb, bfhi(vb.w), a7);
    c0 = fmaf(wc, bflo(vc.x), c0);
    c1 = fmaf(wc, bfhi(vc.x), c1);
    c2 = fmaf(wc, bflo(vc.y), c2);
    c3 = fmaf(wc, bfhi(vc.y), c3);
    c4 = fmaf(wc, bflo(vc.z), c4);
    c5 = fmaf(wc, bfhi(vc.z), c5);
    c6 = fmaf(wc, bflo(vc.w), c6);
    c7 = fmaf(wc, bfhi(vc.w), c7);
    c0 = fmaf(wd, bflo(vd.x), c0);
    c1 = fmaf(wd, bfhi(vd.x), c1);
    c2 = fmaf(wd, bflo(vd.y), c2);
    c3 = fmaf(wd, bfhi(vd.y), c3);
    c4 = fmaf(wd, bflo(vd.z), c4);
    c5 = fmaf(wd, bfhi(vd.z), c5);
    c6 = fmaf(wd, bflo(vd.w), c6);
    c7 = fmaf(wd, bfhi(vd.w), c7);
  }
  a0 += c0; a1 += c1; a2 += c2; a3 += c3;
  a4 += c4; a5 += c5; a6 += c6; a7 += c7;

  a0 += __shfl_xor(a0, 16, 64); a1 += __shfl_xor(a1, 16, 64);
  a2 += __shfl_xor(a2, 16, 64); a3 += __shfl_xor(a3, 16, 64);
  a4 += __shfl_xor(a4, 16, 64); a5 += __shfl_xor(a5, 16, 64);
  a6 += __shfl_xor(a6, 16, 64); a7 += __shfl_xor(a7, 16, 64);
  a0 += __shfl_xor(a0, 32, 64); a1 += __shfl_xor(a1, 32, 64);
  a2 += __shfl_xor(a2, 32, 64); a3 += __shfl_xor(a3, 32, 64);
  a4 += __shfl_xor(a4, 32, 64); a5 += __shfl_xor(a5, 32, 64);
  a6 += __shfl_xor(a6, 32, 64); a7 += __shfl_xor(a7, 32, 64);

  if (grp == 0) {
    float wd2 = -dinv[node] * mscale;
    float r0 = wd2 * a0, r1 = wd2 * a1, r2 = wd2 * a2, r3 = wd2 * a3;
    float r4 = wd2 * a4, r5 = wd2 * a5, r6 = wd2 * a6, r7 = wd2 * a7;
    size_t o = (size_t)node * KH + li * 8;
    if (tx0) {
      const uint4 t = *reinterpret_cast<const uint4*>(tx0 + o);
      r0 -= bflo(t.x); r1 -= bfhi(t.x);
      r2 -= bflo(t.y); r3 -= bfhi(t.y);
      r4 -= bflo(t.z); r5 -= bfhi(t.z);
      r6 -= bflo(t.w); r7 -= bfhi(t.w);
    }
    uint4 w;
    w.x = pack2bf(r0, r1);
    w.y = pack2bf(r2, r3);
    w.z = pack2bf(r4, r5);
    w.w = pack2bf(r6, r7);
    *reinterpret_cast<uint4*>(hout + o) = w;
  }
}

// ---------------- propagation (bf16, 16 ch) with Clenshaw combine ----------------

__global__ __launch_bounds__(256) void k_prop16(
    const ushort* __restrict__ gin, int gstride,
    const ushort* __restrict__ prev, int pstride,
    const ushort* __restrict__ v, int vstride,
    const float* __restrict__ bias,
    ushort* __restrict__ bout, float* __restrict__ fout,
    float scale, const int* __restrict__ row_ptr, const uint32_t* __restrict__ esw,
    const float* __restrict__ dinv, int n) {
  int wave = threadIdx.x >> 6;
  int lane = threadIdx.x & 63;
  int node = blockIdx.x * 4 + wave;
  if (node >= n) return;
  int beg = row_ptr[node], end = row_ptr[node + 1];
  int ch2 = lane & 7;
  int grp = lane >> 3;
  float ax = 0.f, ay = 0.f;
  const ushort* gc = gin + ch2 * 2;
  for (int e = beg + grp; e < end; e += 8) {
    uint32_t u = esw[e];
    float w = bfhi(u);
    int s = (int)(u & 0xffffu);
    uint32_t vv = *reinterpret_cast<const uint32_t*>(gc + (size_t)s * gstride);
    ax = fmaf(w, bflo(vv), ax);
    ay = fmaf(w, bfhi(vv), ay);
  }
#pragma unroll
  for (int off = 8; off < 64; off <<= 1) {
    ax += __shfl_xor(ax, off, 64);
    ay += __shfl_xor(ay, off, 64);
  }
  if (lane < 8) {
    float wsc = -dinv[node] * scale;
    float rx = wsc * ax, ry = wsc * ay;
    if (prev) {
      uint32_t pv = *reinterpret_cast<const uint32_t*>(prev + (size_t)node * pstride + lane * 2);
      rx -= bflo(pv);
      ry -= bfhi(pv);
    }
    uint32_t vv = *reinterpret_cast<const uint32_t*>(v + (size_t)node * vstride + lane * 2);
    rx += bflo(vv);
    ry += bfhi(vv);
    if (fout) {
      fout[(size_t)node * CO + lane * 2]     = rx + bias[lane * 2];
      fout[(size_t)node * CO + lane * 2 + 1] = ry + bias[lane * 2 + 1];
    } else {
      *reinterpret_cast<uint32_t*>(bout + (size_t)node * CO + lane * 2) = pack2bf(rx, ry);
    }
  }
}

// ---------------- MFMA GEMM: out slice0 = A[n x 640] @ W[640 x 128] + bias, relu
// B staged in LDS per 128-K chunk; wave = 2 row-frags (32 rows) x 128 cols,
// 128 rows/block, grid 391. B global traffic 62 MB; 2 indep MFMA chains/wave.

__global__ __launch_bounds__(256) void k_gemm_mfma128(
    const ushort* __restrict__ A, const ushort* __restrict__ Wt,
    const float* __restrict__ bias, ushort* __restrict__ outbf,
    int n, int dorelu) {
  __shared__ __align__(16) ushort Bs[128 * 136];
  int wave = threadIdx.x >> 6, lane = threadIdx.x & 63;
  int rowbase = blockIdx.x * 128 + wave * 32;
  int lr = lane & 15, lk = (lane >> 4) * 8;

  f32x4 acc[2][8];
#pragma unroll
  for (int r = 0; r < 2; ++r)
#pragma unroll
    for (int c = 0; c < 8; ++c) acc[r][c] = (f32x4){0.f, 0.f, 0.f, 0.f};

  int r0 = min(rowbase + lr, n - 1);
  int r1 = min(rowbase + 16 + lr, n - 1);
  const ushort* pa0 = A + (size_t)r0 * KH + lk;
  const ushort* pa1 = A + (size_t)r1 * KH + lk;

  for (int kk = 0; kk < 5; ++kk) {
    __syncthreads();
    for (int u = threadIdx.x; u < 2048; u += 256) {
      int c = u >> 4, j8 = (u & 15) * 8;
      *reinterpret_cast<uint4*>(&Bs[c * 136 + j8]) =
          *reinterpret_cast<const uint4*>(&Wt[(size_t)c * KH + kk * 128 + j8]);
    }
    __syncthreads();
#pragma unroll
    for (int k0 = 0; k0 < 128; k0 += 32) {
      bf16x8 a0 = *reinterpret_cast<const bf16x8*>(pa0 + kk * 128 + k0);
      bf16x8 a1 = *reinterpret_cast<const bf16x8*>(pa1 + kk * 128 + k0);
#pragma unroll
      for (int c = 0; c < 8; ++c) {
        bf16x8 b = *reinterpret_cast<const bf16x8*>(&Bs[(c * 16 + lr) * 136 + k0 + lk]);
        acc[0][c] = __builtin_amdgcn_mfma_f32_16x16x32_bf16(a0, b, acc[0][c], 0, 0, 0);
        acc[1][c] = __builtin_amdgcn_mfma_f32_16x16x32_bf16(a1, b, acc[1][c], 0, 0, 0);
      }
    }
  }

#pragma unroll
  for (int r = 0; r < 2; ++r) {
#pragma unroll
    for (int c = 0; c < 8; ++c) {
      int col = c * 16 + lr;
      float bs = bias[col];
#pragma unroll
      for (int i = 0; i < 4; ++i) {
        int row = rowbase + r * 16 + (lane >> 4) * 4 + i;
        if (row < n) {
          float v = acc[r][c][i] + bs;
          if (dorelu) v = fmaxf(v, 0.f);
          outbf[(size_t)row * KH + col] = f2bf(v);
        }
      }
    }
  }
}

// V[n x 80] bf16 = A_slice0[n x 128] @ Wt3v^T  (Wt3v [80][128], 20KB L1-resident)
__global__ __launch_bounds__(256) void k_gemm_v(
    const ushort* __restrict__ A, const ushort* __restrict__ Wt,
    ushort* __restrict__ V, int n) {
  int wave = threadIdx.x >> 6, lane = threadIdx.x & 63;
  int rowbase = blockIdx.x * 64 + wave * 16;
  int lr = lane & 15, lk = (lane >> 4) * 8;

  f32x4 acc[5];
#pragma unroll
  for (int c = 0; c < 5; ++c) acc[c] = (f32x4){0.f, 0.f, 0.f, 0.f};

  int r0 = min(rowbase + lr, n - 1);
  const ushort* pa = A + (size_t)r0 * KH + lk;
  const ushort* pb = Wt + (size_t)lr * CH + lk;

  for (int k0 = 0; k0 < CH; k0 += 32) {
    bf16x8 a = *reinterpret_cast<const bf16x8*>(pa + k0);
#pragma unroll
    for (int c = 0; c < 5; ++c) {
      bf16x8 b = *reinterpret_cast<const bf16x8*>(pb + (size_t)c * 16 * CH + k0);
      acc[c] = __builtin_amdgcn_mfma_f32_16x16x32_bf16(a, b, acc[c], 0, 0, 0);
    }
  }

#pragma unroll
  for (int c = 0; c < 5; ++c) {
    int col = c * 16 + lr;
#pragma unroll
    for (int i = 0; i < 4; ++i) {
      int row = rowbase + (lane >> 4) * 4 + i;
      if (row < n) V[(size_t)row * 80 + col] = f2bf(acc[c][i]);
    }
  }
}

// ---------------- pooling + log_softmax ----------------

__global__ __launch_bounds__(256) void k_pool(
    const float* __restrict__ h, const int* __restrict__ batch,
    float* __restrict__ sums, float* __restrict__ cnts, int n) {
  __shared__ float sacc[NG * CO];
  __shared__ float scnt[NG];
  for (int i = threadIdx.x; i < NG * CO; i += 256) sacc[i] = 0.f;
  if (threadIdx.x < NG) scnt[threadIdx.x] = 0.f;
  __syncthreads();
  int ch = threadIdx.x & 15;
  int nl = threadIdx.x >> 4;
  int base = blockIdx.x * 1024;
  for (int i = 0; i < 64; ++i) {
    int node = base + i * 16 + nl;
    if (node < n) {
      int g = batch[node];
      atomicAdd(&sacc[g * CO + ch], h[(size_t)node * CO + ch]);
      if (ch == 0) atomicAdd(&scnt[g], 1.f);
    }
  }
  __syncthreads();
  for (int i = threadIdx.x; i < NG * CO; i += 256)
    if (sacc[i] != 0.f) atomicAdd(&sums[i], sacc[i]);
  if (threadIdx.x < NG && scnt[threadIdx.x] != 0.f)
    atomicAdd(&cnts[threadIdx.x], scnt[threadIdx.x]);
}

__global__ void k_lsm(const float* __restrict__ sums, const float* __restrict__ cnts,
                      float* __restrict__ out) {
  int g = threadIdx.x;
  if (g >= NG) return;
  float cnt = fmaxf(cnts[g], 1.f);
  float v[CO];
  float m = -1e30f;
#pragma unroll
  for (int c = 0; c < CO; ++c) { v[c] = sums[g * CO + c] / cnt; m = fmaxf(m, v[c]); }
  float s = 0.f;
#pragma unroll
  for (int c = 0; c < CO; ++c) s += expf(v[c] - m);
  float lse = m + logf(s);
#pragma unroll
  for (int c = 0; c < CO; ++c) out[g * CO + c] = v[c] - lse;
}

// ---------------- host ----------------

static void run_props(ushort* buf, const int* row_ptr, const uint32_t* esw,
                      const float* dinv, hipStream_t stream) {
  dim3 gp((NN + 3) / 4);
  k_prop_bf<<<gp, 256, 0, stream>>>(buf + 0 * CH, nullptr,      buf + 1 * CH, 1.f, row_ptr, esw, dinv, NN);
  k_prop_bf<<<gp, 256, 0, stream>>>(buf + 1 * CH, buf + 0 * CH, buf + 2 * CH, 2.f, row_ptr, esw, dinv, NN);
  k_prop_bf<<<gp, 256, 0, stream>>>(buf + 2 * CH, buf + 1 * CH, buf + 3 * CH, 2.f, row_ptr, esw, dinv, NN);
  k_prop_bf<<<gp, 256, 0, stream>>>(buf + 3 * CH, buf + 2 * CH, buf + 4 * CH, 2.f, row_ptr, esw, dinv, NN);
}

extern "C" void kernel_launch(void* const* d_in, const int* in_sizes, int n_in,
                              void* d_out, int out_size, void* d_ws, size_t ws_size,
                              hipStream_t stream) {
  const float* x   = (const float*)d_in[0];
  const int* src   = (const int*)d_in[1];
  const int* dst   = (const int*)d_in[2];
  const int* batch = (const int*)d_in[3];
  const float* W1  = (const float*)d_in[4];
  const float* b1  = (const float*)d_in[5];
  const float* W2  = (const float*)d_in[6];
  const float* b2  = (const float*)d_in[7];
  const float* W3  = (const float*)d_in[8];
  const float* b3  = (const float*)d_in[9];
  float* out = (float*)d_out;

  char* p = (char*)d_ws;
  auto alloc = [&](size_t bytes) -> void* {
    void* r = (void*)p;
    p += (bytes + 511) & ~(size_t)511;
    return r;
  };
  uint32_t* part   = (uint32_t*)alloc((size_t)NSLICE * NN * 4);
  uint32_t* packed = (uint32_t*)alloc((size_t)NN * 4);
  int* fill        = (int*)alloc((size_t)NN * 4);
  int* row_ptr = (int*)alloc((size_t)(NN + 1) * 4);
  int* bsum    = (int*)alloc(64 * 4);
  uint32_t* esw = (uint32_t*)alloc((size_t)(NE + 16) * 4);  // +16 zero padding
  float* dinv  = (float*)alloc((size_t)NN * 4);
  ushort* bufA = (ushort*)alloc((size_t)NN * KH * 2);
  ushort* bufB = (ushort*)alloc((size_t)NN * KH * 2);
  ushort* Wt1  = (ushort*)alloc((size_t)CH * KH * 2);
  ushort* Wt2  = (ushort*)alloc((size_t)CH * KH * 2);
  ushort* Wt3v = (ushort*)alloc((size_t)80 * CH * 2);
  float* pooled = (float*)alloc((size_t)NG * CO * 4);
  float* cnts   = (float*)alloc((size_t)NG * 4);

  // layer-3 scratch aliases into bufB (free after layer-2 GEMM consumes it)
  ushort* V   = bufB;                       // [NN][80] bf16
  ushort* bb3 = bufB + (size_t)NN * 80;     // [NN][16] bf16
  ushort* bb2 = bb3 + (size_t)NN * CO;
  ushort* bb1 = bb2 + (size_t)NN * CO;
  float*  H3  = (float*)(bb1 + (size_t)NN * CO);  // [NN][16] f32

  hipMemsetAsync(esw + NE, 0, 16 * 4, stream);
  hipMemsetAsync(pooled, 0, (size_t)NG * CO * 4, stream);
  hipMemsetAsync(cnts, 0, (size_t)NG * 4, stream);

  int nsb = (NN + 1023) / 1024;
  k_hist3<<<NRANGE * NSLICE, 1024, 0, stream>>>((const int4*)src, (const int4*)dst,
                                                part, NE / 4);
  k_hreduce<<<(NN + 255) / 256, 256, 0, stream>>>(part, packed, dinv, NN);
  k_scan_a<<<nsb, 1024, 0, stream>>>(packed, row_ptr, bsum, NN);
  k_scan_b<<<1, 64, 0, stream>>>(bsum, nsb);
  k_scan_c<<<nsb, 1024, 0, stream>>>(bsum, row_ptr, fill, NN);
  k_scatter2<<<256, 1024, 0, stream>>>(src, dst, fill, dinv, esw, NE);

  {
    int total = NN * 64 + 2 * KH * CH + 5 * CH * CO;
    k_cvt_all<<<(total + 255) / 256, 256, 0, stream>>>(x, W1, W2, W3, bufA, Wt1, Wt2, Wt3v);
  }

  dim3 gg128((NN + 127) / 128);
  dim3 gg64((NN + 63) / 64);
  dim3 gp4((NN + 3) / 4);

  // layer 1: bufA slices -> bufB slice0 (relu)
  run_props(bufA, row_ptr, esw, dinv, stream);
  k_gemm_mfma128<<<gg128, 256, 0, stream>>>(bufA, Wt1, b1, bufB, NN, 1);

  // layer 2: bufB slices -> bufA slice0 (relu)
  run_props(bufB, row_ptr, esw, dinv, stream);
  k_gemm_mfma128<<<gg128, 256, 0, stream>>>(bufB, Wt2, b2, bufA, NN, 1);

  // layer 3 via Clenshaw: V = h2 @ W3cat; b_k = 2L b_{k+1} - b_{k+2} + v_k
  k_gemm_v<<<gg64, 256, 0, stream>>>(bufA, Wt3v, V, NN);
  k_prop16<<<gp4, 256, 0, stream>>>(V + 64, 80, nullptr, 0, V + 48, 80, nullptr,
                                    bb3, nullptr, 2.f, row_ptr, esw, dinv, NN);
  k_prop16<<<gp4, 256, 0, stream>>>(bb3, CO, V + 64, 80, V + 32, 80, nullptr,
                                    bb2, nullptr, 2.f, row_ptr, esw, dinv, NN);
  k_prop16<<<gp4, 256, 0, stream>>>(bb2, CO, bb3, CO, V + 16, 80, nullptr,
                                    bb1, nullptr, 2.f, row_ptr, esw, dinv, NN);
  k_prop16<<<gp4, 256, 0, stream>>>(bb1, CO, bb2, CO, V + 0, 80, b3,
                                    nullptr, H3, 1.f, row_ptr, esw, dinv, NN);

  // pool + log_softmax
  int pgrid = (NN + 1023) / 1024;
  k_pool<<<pgrid, 256, 0, stream>>>(H3, batch, pooled, cnts, NN);
  k_lsm<<<1, 64, 0, stream>>>(pooled, cnts, out);
}

// Round 20
// 512.160 us; speedup vs baseline: 1.0220x; 1.0220x over previous
//
#include <hip/hip_runtime.h>
#include <stdint.h>

#define NN 50000
#define NE 800000
#define NG 64
#define CH 128
#define CO 16
#define KH 640    // 5 * 128
#define HRB 4096  // hist node-range per block
#define NRANGE 13 // ceil(NN / HRB)
#define NSLICE 20 // edge slices (13*20 = 260 blocks)
#define SCR 6250  // scatter dst-range per XCD (NN/8)

typedef __attribute__((ext_vector_type(8))) short bf16x8;
typedef __attribute__((ext_vector_type(4))) float f32x4;

__device__ __forceinline__ ushort f2bf(float f) {
  uint32_t u = __float_as_uint(f);
  u += 0x7fffu + ((u >> 16) & 1u);
  return (ushort)(u >> 16);
}
__device__ __forceinline__ float bflo(uint32_t v) { return __uint_as_float(v << 16); }
__device__ __forceinline__ float bfhi(uint32_t v) { return __uint_as_float(v & 0xffff0000u); }

// pack two f32 -> (bf16(hi)<<16)|bf16(lo) in 3 VALU ops (round-half-up)
__device__ __forceinline__ uint32_t pack2bf(float lo, float hi) {
  uint32_t ul = __float_as_uint(lo) + 0x8000u;
  uint32_t uh = __float_as_uint(hi) + 0x8000u;
  return __builtin_amdgcn_perm(uh, ul, 0x07060302u);
}

// ---------------- graph preprocessing ----------------

__global__ __launch_bounds__(1024) void k_hist3(const int4* __restrict__ src4,
                                                const int4* __restrict__ dst4,
                                                uint32_t* __restrict__ part,
                                                int nquad) {
  __shared__ uint32_t h[HRB];
  int range = blockIdx.x / NSLICE;
  int slice = blockIdx.x % NSLICE;
  int lo = range * HRB;
  int q0 = slice * (nquad / NSLICE);
  int q1 = q0 + (nquad / NSLICE);
  for (int i = threadIdx.x; i < HRB; i += 1024) h[i] = 0;
  __syncthreads();
  for (int e = q0 + threadIdx.x; e < q1; e += 1024) {
    int4 s = src4[e];
    int4 d = dst4[e];
    int t;
    t = s.x - lo; if ((unsigned)t < HRB) atomicAdd(&h[t], 1u);
    t = s.y - lo; if ((unsigned)t < HRB) atomicAdd(&h[t], 1u);
    t = s.z - lo; if ((unsigned)t < HRB) atomicAdd(&h[t], 1u);
    t = s.w - lo; if ((unsigned)t < HRB) atomicAdd(&h[t], 1u);
    t = d.x - lo; if ((unsigned)t < HRB) atomicAdd(&h[t], 65536u);
    t = d.y - lo; if ((unsigned)t < HRB) atomicAdd(&h[t], 65536u);
    t = d.z - lo; if ((unsigned)t < HRB) atomicAdd(&h[t], 65536u);
    t = d.w - lo; if ((unsigned)t < HRB) atomicAdd(&h[t], 65536u);
  }
  __syncthreads();
  uint32_t* pr = part + (size_t)slice * NN;
  for (int i = threadIdx.x; i < HRB && lo + i < NN; i += 1024)
    pr[lo + i] = h[i];
}

__global__ __launch_bounds__(256) void k_hreduce(const uint32_t* __restrict__ part,
                                                 uint32_t* __restrict__ packed,
                                                 float* __restrict__ dinv, int n) {
  int i = blockIdx.x * 256 + threadIdx.x;
  if (i >= n) return;
  uint32_t acc = 0;
#pragma unroll
  for (int s = 0; s < NSLICE; ++s) acc += part[(size_t)s * NN + i];
  packed[i] = acc;
  int deg = (int)(acc & 0xffffu);
  dinv[i] = deg > 0 ? rsqrtf((float)deg) : 0.f;
}

__global__ __launch_bounds__(1024) void k_scan_a(const uint32_t* __restrict__ packed,
                                                 int* __restrict__ row_ptr,
                                                 int* __restrict__ bsum, int n) {
  __shared__ int sm[1024];
  int i = blockIdx.x * 1024 + threadIdx.x;
  int v = (i < n) ? (int)(packed[i] >> 16) : 0;
  sm[threadIdx.x] = v;
  __syncthreads();
  for (int off = 1; off < 1024; off <<= 1) {
    int t = (threadIdx.x >= off) ? sm[threadIdx.x - off] : 0;
    __syncthreads();
    sm[threadIdx.x] += t;
    __syncthreads();
  }
  if (i < n) row_ptr[i + 1] = sm[threadIdx.x];
  if (threadIdx.x == 1023) bsum[blockIdx.x] = sm[1023];
}

__global__ void k_scan_b(int* __restrict__ bsum, int nb) {
  if (threadIdx.x == 0) {
    int off = 0;
    for (int i = 0; i < nb; ++i) { int t = bsum[i]; bsum[i] = off; off += t; }
  }
}

__global__ __launch_bounds__(1024) void k_scan_c(const int* __restrict__ bsum,
                                                 int* __restrict__ row_ptr,
                                                 int* __restrict__ fill, int n) {
  int i = blockIdx.x * 1024 + threadIdx.x;
  if (i == 0) { row_ptr[0] = 0; fill[0] = 0; }
  if (i < n) {
    int rp = row_ptr[i + 1] + bsum[blockIdx.x];
    row_ptr[i + 1] = rp;
    if (i + 1 < n) fill[i + 1] = rp;
  }
}

// XCD-partitioned scatter: block (g = blockIdx&7 -> XCD, j = blockIdx>>3).
// 512 blocks (2/CU) to hide atomic round-trip latency; range g's fill + esw
// region stay in XCD g's L2.
__global__ __launch_bounds__(1024) void k_scatter2(
    const int* __restrict__ src, const int* __restrict__ dst,
    int* __restrict__ fill, const float* __restrict__ dinv,
    uint32_t* __restrict__ esw, int E) {
  int g = blockIdx.x & 7;
  int j = blockIdx.x >> 3;                 // 0..63
  int lo = g * SCR, hi = min(lo + SCR, NN);
  int per = E / 64;                        // 12500
  int e0 = j * per, e1 = e0 + per;
  for (int e = e0 + threadIdx.x; e < e1; e += 1024) {
    int d = dst[e];
    if (d >= lo && d < hi) {
      int s = src[e];
      int pos = atomicAdd(&fill[d], 1);
      esw[pos] = (uint32_t)s | ((uint32_t)f2bf(dinv[s]) << 16);
    }
  }
}

// ---------------- conversions (fused, identity k-order) ----------------

__global__ __launch_bounds__(256) void k_cvt_all(
    const float* __restrict__ x, const float* __restrict__ W1,
    const float* __restrict__ W2, const float* __restrict__ W3,
    ushort* __restrict__ bufA, ushort* __restrict__ Wt1,
    ushort* __restrict__ Wt2, ushort* __restrict__ Wt3v) {
  const int R1 = NN * 64;
  const int R2 = KH * CH;
  int t = blockIdx.x * 256 + threadIdx.x;
  if (t < R1) {
    int node = t >> 6, p = t & 63;
    float2 v = reinterpret_cast<const float2*>(x)[t];
    *reinterpret_cast<uint32_t*>(bufA + (size_t)node * KH + p * 2) =
        pack2bf(v.x, v.y);
    return;
  }
  t -= R1;
  if (t < 2 * R2) {
    const float* W = (t < R2) ? W1 : W2;
    ushort* Wt = (t < R2) ? Wt1 : Wt2;
    int u = (t < R2) ? t : t - R2;
    int kc = u >> 7, nc = u & 127;
    Wt[(size_t)nc * KH + kc] = f2bf(W[u]);
    return;
  }
  t -= 2 * R2;
  if (t < 5 * CH * CO) {
    int k = t >> 11, r = t & 2047;
    int c = r >> 4, j = r & 15;
    Wt3v[(size_t)(k * CO + j) * CH + c] = f2bf(W3[t]);
  }
}

// ---------------- propagation (bf16, 128 ch), edge-parallel wide gathers ----

__global__ __launch_bounds__(256) void k_prop_bf(
    const ushort* __restrict__ hin, const ushort* __restrict__ tx0,
    ushort* __restrict__ hout, float mscale,
    const int* __restrict__ row_ptr, const uint32_t* __restrict__ esw,
    const float* __restrict__ dinv, int n) {
  int wave = threadIdx.x >> 6;
  int lane = threadIdx.x & 63;
  int node = blockIdx.x * 4 + wave;
  if (node >= n) return;
  int beg = row_ptr[node], end = row_ptr[node + 1];
  int grp = lane >> 4, li = lane & 15;
  const ushort* hc = hin + li * 8;

  float a0 = 0.f, a1 = 0.f, a2 = 0.f, a3 = 0.f;
  float a4 = 0.f, a5 = 0.f, a6 = 0.f, a7 = 0.f;
  float c0 = 0.f, c1 = 0.f, c2 = 0.f, c3 = 0.f;
  float c4 = 0.f, c5 = 0.f, c6 = 0.f, c7 = 0.f;

  for (int e0 = beg; e0 < end; e0 += 16) {
    int ea = e0 + grp;
    uint32_t ua = esw[ea];
    uint32_t ub = esw[ea + 4];
    uint32_t uc = esw[ea + 8];
    uint32_t ud = esw[ea + 12];
    float wa = (ea < end) ? bfhi(ua) : 0.f;
    float wb = (ea + 4 < end) ? bfhi(ub) : 0.f;
    float wc = (ea + 8 < end) ? bfhi(uc) : 0.f;
    float wd = (ea + 12 < end) ? bfhi(ud) : 0.f;
    const uint4 va = *reinterpret_cast<const uint4*>(hc + (size_t)(ua & 0xffffu) * KH);
    const uint4 vb = *reinterpret_cast<const uint4*>(hc + (size_t)(ub & 0xffffu) * KH);
    const uint4 vc = *reinterpret_cast<const uint4*>(hc + (size_t)(uc & 0xffffu) * KH);
    const uint4 vd = *reinterpret_cast<const uint4*>(hc + (size_t)(ud & 0xffffu) * KH);
    a0 = fmaf(wa, bflo(va.x), a0);
    a1 = fmaf(wa, bfhi(va.x), a1);
    a2 = fmaf(wa, bflo(va.y), a2);
    a3 = fmaf(wa, bfhi(va.y), a3);
    a4 = fmaf(wa, bflo(va.z), a4);
    a5 = fmaf(wa, bfhi(va.z), a5);
    a6 = fmaf(wa, bflo(va.w), a6);
    a7 = fmaf(wa, bfhi(va.w), a7);
    a0 = fmaf(wb, bflo(vb.x), a0);
    a1 = fmaf(wb, bfhi(vb.x), a1);
    a2 = fmaf(wb, bflo(vb.y), a2);
    a3 = fmaf(wb, bfhi(vb.y), a3);
    a4 = fmaf(wb, bflo(vb.z), a4);
    a5 = fmaf(wb, bfhi(vb.z), a5);
    a6 = fmaf(wb, bflo(vb.w), a6);
    a7 = fmaf(wb, bfhi(vb.w), a7);
    c0 = fmaf(wc, bflo(vc.x), c0);
    c1 = fmaf(wc, bfhi(vc.x), c1);
    c2 = fmaf(wc, bflo(vc.y), c2);
    c3 = fmaf(wc, bfhi(vc.y), c3);
    c4 = fmaf(wc, bflo(vc.z), c4);
    c5 = fmaf(wc, bfhi(vc.z), c5);
    c6 = fmaf(wc, bflo(vc.w), c6);
    c7 = fmaf(wc, bfhi(vc.w), c7);
    c0 = fmaf(wd, bflo(vd.x), c0);
    c1 = fmaf(wd, bfhi(vd.x), c1);
    c2 = fmaf(wd, bflo(vd.y), c2);
    c3 = fmaf(wd, bfhi(vd.y), c3);
    c4 = fmaf(wd, bflo(vd.z), c4);
    c5 = fmaf(wd, bfhi(vd.z), c5);
    c6 = fmaf(wd, bflo(vd.w), c6);
    c7 = fmaf(wd, bfhi(vd.w), c7);
  }
  a0 += c0; a1 += c1; a2 += c2; a3 += c3;
  a4 += c4; a5 += c5; a6 += c6; a7 += c7;

  a0 += __shfl_xor(a0, 16, 64); a1 += __shfl_xor(a1, 16, 64);
  a2 += __shfl_xor(a2, 16, 64); a3 += __shfl_xor(a3, 16, 64);
  a4 += __shfl_xor(a4, 16, 64); a5 += __shfl_xor(a5, 16, 64);
  a6 += __shfl_xor(a6, 16, 64); a7 += __shfl_xor(a7, 16, 64);
  a0 += __shfl_xor(a0, 32, 64); a1 += __shfl_xor(a1, 32, 64);
  a2 += __shfl_xor(a2, 32, 64); a3 += __shfl_xor(a3, 32, 64);
  a4 += __shfl_xor(a4, 32, 64); a5 += __shfl_xor(a5, 32, 64);
  a6 += __shfl_xor(a6, 32, 64); a7 += __shfl_xor(a7, 32, 64);

  if (grp == 0) {
    float wd2 = -dinv[node] * mscale;
    float r0 = wd2 * a0, r1 = wd2 * a1, r2 = wd2 * a2, r3 = wd2 * a3;
    float r4 = wd2 * a4, r5 = wd2 * a5, r6 = wd2 * a6, r7 = wd2 * a7;
    size_t o = (size_t)node * KH + li * 8;
    if (tx0) {
      const uint4 t = *reinterpret_cast<const uint4*>(tx0 + o);
      r0 -= bflo(t.x); r1 -= bfhi(t.x);
      r2 -= bflo(t.y); r3 -= bfhi(t.y);
      r4 -= bflo(t.z); r5 -= bfhi(t.z);
      r6 -= bflo(t.w); r7 -= bfhi(t.w);
    }
    uint4 w;
    w.x = pack2bf(r0, r1);
    w.y = pack2bf(r2, r3);
    w.z = pack2bf(r4, r5);
    w.w = pack2bf(r6, r7);
    *reinterpret_cast<uint4*>(hout + o) = w;
  }
}

// ---------------- propagation (bf16, 16 ch) with Clenshaw combine ----------------

__global__ __launch_bounds__(256) void k_prop16(
    const ushort* __restrict__ gin, int gstride,
    const ushort* __restrict__ prev, int pstride,
    const ushort* __restrict__ v, int vstride,
    const float* __restrict__ bias,
    ushort* __restrict__ bout, float* __restrict__ fout,
    float scale, const int* __restrict__ row_ptr, const uint32_t* __restrict__ esw,
    const float* __restrict__ dinv, int n) {
  int wave = threadIdx.x >> 6;
  int lane = threadIdx.x & 63;
  int node = blockIdx.x * 4 + wave;
  if (node >= n) return;
  int beg = row_ptr[node], end = row_ptr[node + 1];
  int ch2 = lane & 7;
  int grp = lane >> 3;
  float ax = 0.f, ay = 0.f;
  const ushort* gc = gin + ch2 * 2;
  for (int e = beg + grp; e < end; e += 8) {
    uint32_t u = esw[e];
    float w = bfhi(u);
    int s = (int)(u & 0xffffu);
    uint32_t vv = *reinterpret_cast<const uint32_t*>(gc + (size_t)s * gstride);
    ax = fmaf(w, bflo(vv), ax);
    ay = fmaf(w, bfhi(vv), ay);
  }
#pragma unroll
  for (int off = 8; off < 64; off <<= 1) {
    ax += __shfl_xor(ax, off, 64);
    ay += __shfl_xor(ay, off, 64);
  }
  if (lane < 8) {
    float wsc = -dinv[node] * scale;
    float rx = wsc * ax, ry = wsc * ay;
    if (prev) {
      uint32_t pv = *reinterpret_cast<const uint32_t*>(prev + (size_t)node * pstride + lane * 2);
      rx -= bflo(pv);
      ry -= bfhi(pv);
    }
    uint32_t vv = *reinterpret_cast<const uint32_t*>(v + (size_t)node * vstride + lane * 2);
    rx += bflo(vv);
    ry += bfhi(vv);
    if (fout) {
      fout[(size_t)node * CO + lane * 2]     = rx + bias[lane * 2];
      fout[(size_t)node * CO + lane * 2 + 1] = ry + bias[lane * 2 + 1];
    } else {
      *reinterpret_cast<uint32_t*>(bout + (size_t)node * CO + lane * 2) = pack2bf(rx, ry);
    }
  }
}

// ---------------- MFMA GEMM: out slice0 = A[n x 640] @ W[640 x 128] + bias, relu
// B staged in LDS per 128-K chunk (32KB, pad 136); wave = 16 rows x 128 cols,
// 64 rows/block, grid 782 (~12 waves/CU). [round-18 measured-best shape]

__global__ __launch_bounds__(256) void k_gemm_mfma128(
    const ushort* __restrict__ A, const ushort* __restrict__ Wt,
    const float* __restrict__ bias, ushort* __restrict__ outbf,
    int n, int dorelu) {
  __shared__ __align__(16) ushort Bs[128 * 136];
  int wave = threadIdx.x >> 6, lane = threadIdx.x & 63;
  int rowbase = blockIdx.x * 64 + wave * 16;
  int lr = lane & 15, lk = (lane >> 4) * 8;

  f32x4 acc[8];
#pragma unroll
  for (int c = 0; c < 8; ++c) acc[c] = (f32x4){0.f, 0.f, 0.f, 0.f};

  int r0 = min(rowbase + lr, n - 1);
  const ushort* pa0 = A + (size_t)r0 * KH + lk;

  for (int kk = 0; kk < 5; ++kk) {
    __syncthreads();
    for (int u = threadIdx.x; u < 2048; u += 256) {
      int c = u >> 4, j8 = (u & 15) * 8;
      *reinterpret_cast<uint4*>(&Bs[c * 136 + j8]) =
          *reinterpret_cast<const uint4*>(&Wt[(size_t)c * KH + kk * 128 + j8]);
    }
    __syncthreads();
    const ushort* pA = pa0 + kk * 128;
#pragma unroll
    for (int k0 = 0; k0 < 128; k0 += 32) {
      bf16x8 a0 = *reinterpret_cast<const bf16x8*>(pA + k0);
#pragma unroll
      for (int c = 0; c < 8; ++c) {
        bf16x8 b = *reinterpret_cast<const bf16x8*>(&Bs[(c * 16 + lr) * 136 + k0 + lk]);
        acc[c] = __builtin_amdgcn_mfma_f32_16x16x32_bf16(a0, b, acc[c], 0, 0, 0);
      }
    }
  }

#pragma unroll
  for (int c = 0; c < 8; ++c) {
    int col = c * 16 + lr;
    float bs = bias[col];
#pragma unroll
    for (int i = 0; i < 4; ++i) {
      int row = rowbase + (lane >> 4) * 4 + i;
      if (row < n) {
        float v = acc[c][i] + bs;
        if (dorelu) v = fmaxf(v, 0.f);
        outbf[(size_t)row * KH + col] = f2bf(v);
      }
    }
  }
}

// V[n x 80] bf16 = A_slice0[n x 128] @ Wt3v^T  (Wt3v [80][128], 20KB L1-resident)
__global__ __launch_bounds__(256) void k_gemm_v(
    const ushort* __restrict__ A, const ushort* __restrict__ Wt,
    ushort* __restrict__ V, int n) {
  int wave = threadIdx.x >> 6, lane = threadIdx.x & 63;
  int rowbase = blockIdx.x * 64 + wave * 16;
  int lr = lane & 15, lk = (lane >> 4) * 8;

  f32x4 acc[5];
#pragma unroll
  for (int c = 0; c < 5; ++c) acc[c] = (f32x4){0.f, 0.f, 0.f, 0.f};

  int r0 = min(rowbase + lr, n - 1);
  const ushort* pa = A + (size_t)r0 * KH + lk;
  const ushort* pb = Wt + (size_t)lr * CH + lk;

  for (int k0 = 0; k0 < CH; k0 += 32) {
    bf16x8 a = *reinterpret_cast<const bf16x8*>(pa + k0);
#pragma unroll
    for (int c = 0; c < 5; ++c) {
      bf16x8 b = *reinterpret_cast<const bf16x8*>(pb + (size_t)c * 16 * CH + k0);
      acc[c] = __builtin_amdgcn_mfma_f32_16x16x32_bf16(a, b, acc[c], 0, 0, 0);
    }
  }

#pragma unroll
  for (int c = 0; c < 5; ++c) {
    int col = c * 16 + lr;
#pragma unroll
    for (int i = 0; i < 4; ++i) {
      int row = rowbase + (lane >> 4) * 4 + i;
      if (row < n) V[(size_t)row * 80 + col] = f2bf(acc[c][i]);
    }
  }
}

// ---------------- pooling + log_softmax ----------------

__global__ __launch_bounds__(256) void k_pool(
    const float* __restrict__ h, const int* __restrict__ batch,
    float* __restrict__ sums, float* __restrict__ cnts, int n) {
  __shared__ float sacc[NG * CO];
  __shared__ float scnt[NG];
  for (int i = threadIdx.x; i < NG * CO; i += 256) sacc[i] = 0.f;
  if (threadIdx.x < NG) scnt[threadIdx.x] = 0.f;
  __syncthreads();
  int ch = threadIdx.x & 15;
  int nl = threadIdx.x >> 4;
  int base = blockIdx.x * 1024;
  for (int i = 0; i < 64; ++i) {
    int node = base + i * 16 + nl;
    if (node < n) {
      int g = batch[node];
      atomicAdd(&sacc[g * CO + ch], h[(size_t)node * CO + ch]);
      if (ch == 0) atomicAdd(&scnt[g], 1.f);
    }
  }
  __syncthreads();
  for (int i = threadIdx.x; i < NG * CO; i += 256)
    if (sacc[i] != 0.f) atomicAdd(&sums[i], sacc[i]);
  if (threadIdx.x < NG && scnt[threadIdx.x] != 0.f)
    atomicAdd(&cnts[threadIdx.x], scnt[threadIdx.x]);
}

__global__ void k_lsm(const float* __restrict__ sums, const float* __restrict__ cnts,
                      float* __restrict__ out) {
  int g = threadIdx.x;
  if (g >= NG) return;
  float cnt = fmaxf(cnts[g], 1.f);
  float v[CO];
  float m = -1e30f;
#pragma unroll
  for (int c = 0; c < CO; ++c) { v[c] = sums[g * CO + c] / cnt; m = fmaxf(m, v[c]); }
  float s = 0.f;
#pragma unroll
  for (int c = 0; c < CO; ++c) s += expf(v[c] - m);
  float lse = m + logf(s);
#pragma unroll
  for (int c = 0; c < CO; ++c) out[g * CO + c] = v[c] - lse;
}

// ---------------- host ----------------

static void run_props(ushort* buf, const int* row_ptr, const uint32_t* esw,
                      const float* dinv, hipStream_t stream) {
  dim3 gp((NN + 3) / 4);
  k_prop_bf<<<gp, 256, 0, stream>>>(buf + 0 * CH, nullptr,      buf + 1 * CH, 1.f, row_ptr, esw, dinv, NN);
  k_prop_bf<<<gp, 256, 0, stream>>>(buf + 1 * CH, buf + 0 * CH, buf + 2 * CH, 2.f, row_ptr, esw, dinv, NN);
  k_prop_bf<<<gp, 256, 0, stream>>>(buf + 2 * CH, buf + 1 * CH, buf + 3 * CH, 2.f, row_ptr, esw, dinv, NN);
  k_prop_bf<<<gp, 256, 0, stream>>>(buf + 3 * CH, buf + 2 * CH, buf + 4 * CH, 2.f, row_ptr, esw, dinv, NN);
}

extern "C" void kernel_launch(void* const* d_in, const int* in_sizes, int n_in,
                              void* d_out, int out_size, void* d_ws, size_t ws_size,
                              hipStream_t stream) {
  const float* x   = (const float*)d_in[0];
  const int* src   = (const int*)d_in[1];
  const int* dst   = (const int*)d_in[2];
  const int* batch = (const int*)d_in[3];
  const float* W1  = (const float*)d_in[4];
  const float* b1  = (const float*)d_in[5];
  const float* W2  = (const float*)d_in[6];
  const float* b2  = (const float*)d_in[7];
  const float* W3  = (const float*)d_in[8];
  const float* b3  = (const float*)d_in[9];
  float* out = (float*)d_out;

  char* p = (char*)d_ws;
  auto alloc = [&](size_t bytes) -> void* {
    void* r = (void*)p;
    p += (bytes + 511) & ~(size_t)511;
    return r;
  };
  uint32_t* part   = (uint32_t*)alloc((size_t)NSLICE * NN * 4);
  uint32_t* packed = (uint32_t*)alloc((size_t)NN * 4);
  int* fill        = (int*)alloc((size_t)NN * 4);
  int* row_ptr = (int*)alloc((size_t)(NN + 1) * 4);
  int* bsum    = (int*)alloc(64 * 4);
  uint32_t* esw = (uint32_t*)alloc((size_t)(NE + 16) * 4);  // +16 zero padding
  float* dinv  = (float*)alloc((size_t)NN * 4);
  ushort* bufA = (ushort*)alloc((size_t)NN * KH * 2);
  ushort* bufB = (ushort*)alloc((size_t)NN * KH * 2);
  ushort* Wt1  = (ushort*)alloc((size_t)CH * KH * 2);
  ushort* Wt2  = (ushort*)alloc((size_t)CH * KH * 2);
  ushort* Wt3v = (ushort*)alloc((size_t)80 * CH * 2);
  float* pooled = (float*)alloc((size_t)NG * CO * 4);
  float* cnts   = (float*)alloc((size_t)NG * 4);

  // layer-3 scratch aliases into bufB (free after layer-2 GEMM consumes it)
  ushort* V   = bufB;                       // [NN][80] bf16
  ushort* bb3 = bufB + (size_t)NN * 80;     // [NN][16] bf16
  ushort* bb2 = bb3 + (size_t)NN * CO;
  ushort* bb1 = bb2 + (size_t)NN * CO;
  float*  H3  = (float*)(bb1 + (size_t)NN * CO);  // [NN][16] f32

  hipMemsetAsync(esw + NE, 0, 16 * 4, stream);
  hipMemsetAsync(pooled, 0, (size_t)NG * CO * 4, stream);
  hipMemsetAsync(cnts, 0, (size_t)NG * 4, stream);

  int nsb = (NN + 1023) / 1024;
  k_hist3<<<NRANGE * NSLICE, 1024, 0, stream>>>((const int4*)src, (const int4*)dst,
                                                part, NE / 4);
  k_hreduce<<<(NN + 255) / 256, 256, 0, stream>>>(part, packed, dinv, NN);
  k_scan_a<<<nsb, 1024, 0, stream>>>(packed, row_ptr, bsum, NN);
  k_scan_b<<<1, 64, 0, stream>>>(bsum, nsb);
  k_scan_c<<<nsb, 1024, 0, stream>>>(bsum, row_ptr, fill, NN);
  k_scatter2<<<512, 1024, 0, stream>>>(src, dst, fill, dinv, esw, NE);

  {
    int total = NN * 64 + 2 * KH * CH + 5 * CH * CO;
    k_cvt_all<<<(total + 255) / 256, 256, 0, stream>>>(x, W1, W2, W3, bufA, Wt1, Wt2, Wt3v);
  }

  dim3 gg64((NN + 63) / 64);
  dim3 gp4((NN + 3) / 4);

  // layer 1: bufA slices -> bufB slice0 (relu)
  run_props(bufA, row_ptr, esw, dinv, stream);
  k_gemm_mfma128<<<gg64, 256, 0, stream>>>(bufA, Wt1, b1, bufB, NN, 1);

  // layer 2: bufB slices -> bufA slice0 (relu)
  run_props(bufB, row_ptr, esw, dinv, stream);
  k_gemm_mfma128<<<gg64, 256, 0, stream>>>(bufB, Wt2, b2, bufA, NN, 1);

  // layer 3 via Clenshaw: V = h2 @ W3cat; b_k = 2L b_{k+1} - b_{k+2} + v_k
  k_gemm_v<<<gg64, 256, 0, stream>>>(bufA, Wt3v, V, NN);
  k_prop16<<<gp4, 256, 0, stream>>>(V + 64, 80, nullptr, 0, V + 48, 80, nullptr,
                                    bb3, nullptr, 2.f, row_ptr, esw, dinv, NN);
  k_prop16<<<gp4, 256, 0, stream>>>(bb3, CO, V + 64, 80, V + 32, 80, nullptr,
                                    bb2, nullptr, 2.f, row_ptr, esw, dinv, NN);
  k_prop16<<<gp4, 256, 0, stream>>>(bb2, CO, bb3, CO, V + 16, 80, nullptr,
                                    bb1, nullptr, 2.f, row_ptr, esw, dinv, NN);
  k_prop16<<<gp4, 256, 0, stream>>>(bb1, CO, bb2, CO, V + 0, 80, b3,
                                    nullptr, H3, 1.f, row_ptr, esw, dinv, NN);

  // pool + log_softmax
  int pgrid = (NN + 1023) / 1024;
  k_pool<<<pgrid, 256, 0, stream>>>(H3, batch, pooled, cnts, NN);
  k_lsm<<<1, 64, 0, stream>>>(pooled, cnts, out);
}